// Round 1
// baseline (287.549 us; speedup 1.0000x reference)
//
#include <hip/hip_runtime.h>

typedef _Float16 v8h __attribute__((ext_vector_type(8)));
typedef _Float16 v4h __attribute__((ext_vector_type(4)));
typedef float    v4f __attribute__((ext_vector_type(4)));

#define HH 192
#define WW 192
#define PIX (HH*WW)

// ---------------- ws layout (bytes) ----------------
// feat : PIX*64*2              = 4,718,592
// G    : PIX*256*2             = 18,874,368
// qtab : 262144*16             = 4,194,304
// w0p  : 16nt*18ks*64*8*2      = 294,912
// w1p/w2p/w3p : 16*8*64*8*2    = 131,072 each
// w4p  : 1*8*64*8*2            = 8,192
// ewt  : 27*64*4               = 6,912
static const size_t OFF_FEAT = 0;
static const size_t OFF_G    = 4718592;
static const size_t OFF_QTAB = 23592960;
static const size_t OFF_W0P  = 27787264;
static const size_t OFF_W1P  = 28082176;
static const size_t OFF_W2P  = 28213248;
static const size_t OFF_W3P  = 28344320;
static const size_t OFF_W4P  = 28475392;
static const size_t OFF_EWT  = 28483584;

// ---------------- weight prepack ----------------
// dst[((nt*KS+ks)*64 + lane)*8 + j] = (fp16) src[ksrc(k)*N + nt*16+(lane&15)]
// with k = ks*32 + (lane>>4)*8 + j.  mode 1: packed-k = n*64+c -> src row c*9+n.
__global__ __launch_bounds__(256) void k_pack(const float* __restrict__ src,
    _Float16* __restrict__ dst, int K, int N, int KS, int NT, int mode) {
  int gid = blockIdx.x * 256 + threadIdx.x;
  int total = NT * KS * 512;
  if (gid >= total) return;
  int j  = gid & 7;
  int l  = (gid >> 3) & 63;
  int ks = (gid >> 9) % KS;
  int nt = gid / (512 * KS);
  int k   = ks * 32 + ((l >> 4) << 3) + j;
  int col = nt * 16 + (l & 15);
  float v = 0.f;
  if (col < N && k < K) {
    int row = (mode == 1) ? ((k & 63) * 9 + (k >> 6)) : k;
    v = src[row * N + col];
  }
  dst[gid] = (_Float16)v;
}

// ewt[tap*64 + c] = ew[c*27 + tap]
__global__ __launch_bounds__(256) void k_packew(const float* __restrict__ ew,
                                                float* __restrict__ ewt) {
  int i = blockIdx.x * 256 + threadIdx.x;
  if (i >= 27 * 64) return;
  int tap = i >> 6, c = i & 63;
  ewt[i] = ew[c * 27 + tap];
}

// ---------------- conv encoder: feat[p][c] fp16 ----------------
__global__ __launch_bounds__(256) void k_conv(const float* __restrict__ inp,
    const float* __restrict__ ewt, const float* __restrict__ eb,
    _Float16* __restrict__ feat) {
  int gid = blockIdx.x * 256 + threadIdx.x;
  int p = gid >> 6, c = gid & 63;
  int y = p / WW, x = p - y * WW;
  float acc = eb[c];
  #pragma unroll
  for (int ci = 0; ci < 3; ++ci) {
    #pragma unroll
    for (int dy = 0; dy < 3; ++dy) {
      #pragma unroll
      for (int dx = 0; dx < 3; ++dx) {
        int yy = y + dy - 1, xx = x + dx - 1;
        float v = (yy >= 0 && yy < HH && xx >= 0 && xx < WW)
                      ? inp[ci * PIX + yy * WW + xx] : 0.f;
        acc += v * ewt[(ci * 9 + dy * 3 + dx) * 64 + c];
      }
    }
  }
  feat[p * 64 + c] = (_Float16)acc;
}

// ---------------- query setup: qtab[s] = {lin, rely, relx, wk} ----------------
__global__ __launch_bounds__(256) void k_qsetup(const float* __restrict__ coord,
                                                float4* __restrict__ qtab) {
  int q = blockIdx.x * 256 + threadIdx.x;
  float cy = coord[q * 2 + 0], cx = coord[q * 2 + 1];
  const float eps = 1e-6f;
  const float rad = (float)(1.0 / 192.0);
  const float CLO = (float)(-1.0 + 1e-6);
  const float CHI = (float)(1.0 - 1e-6);
  const float S2  = (float)(2.0 / 192.0);
  float ry[4], rx[4], ar[4];
  int   li[4];
  #pragma unroll
  for (int k = 0; k < 4; ++k) {
    float oy = (k < 2) ? -rad : rad;   // offs = [[-1,-1],[-1,1],[1,-1],[1,1]]
    float ox = (k & 1) ? rad : -rad;
    // exact replication of JAX f32 op order (no FMA contraction):
    float cey = __fadd_rn(__fadd_rn(cy, oy), eps);
    float cex = __fadd_rn(__fadd_rn(cx, ox), eps);
    cey = fminf(fmaxf(cey, CLO), CHI);
    cex = fminf(fmaxf(cex, CLO), CHI);
    float ty = __fmul_rn(__fsub_rn(__fmul_rn(__fadd_rn(cey, 1.0f), 192.0f), 1.0f), 0.5f);
    float tx = __fmul_rn(__fsub_rn(__fmul_rn(__fadd_rn(cex, 1.0f), 192.0f), 1.0f), 0.5f);
    float fy = fminf(fmaxf(rintf(ty), 0.f), 191.f);   // rintf = round-half-even
    float fx = fminf(fmaxf(rintf(tx), 0.f), 191.f);
    float qy = __fsub_rn(__fmul_rn(__fadd_rn(fy, 0.5f), S2), 1.0f);
    float qx = __fsub_rn(__fmul_rn(__fadd_rn(fx, 0.5f), S2), 1.0f);
    ry[k] = __fmul_rn(__fsub_rn(cy, qy), 192.0f);
    rx[k] = __fmul_rn(__fsub_rn(cx, qx), 192.0f);
    ar[k] = fabsf(ry[k] * rx[k]) + 1e-9f;
    li[k] = (int)fy * WW + (int)fx;
  }
  float tot = ar[0] + ar[1] + ar[2] + ar[3];
  #pragma unroll
  for (int k = 0; k < 4; ++k) {
    float wk = ar[3 - k] / tot;                    // areas[::-1]
    qtab[q * 4 + k] = make_float4(__int_as_float(li[k]), ry[k], rx[k], wk);
  }
}

// ---------------- G-GEMM: G[p][n] = im2col(feat)[p] @ W0f + b0 ----------------
// M-tile 32, N=256, K=576 (packed k = n*64+c). 4 waves, each a 64-col slice.
__global__ __launch_bounds__(256) void k_ggemm(const _Float16* __restrict__ feat,
    const _Float16* __restrict__ w0p, const float* __restrict__ b0,
    _Float16* __restrict__ G) {
  __shared__ __align__(16) char lds[32 * 1152];
  int t = threadIdx.x, blk = blockIdx.x;
  int lane = t & 63, wv = t >> 6;
  // stage im2col rows (32 rows x 9 nbrs x 128B), swizzled
  #pragma unroll
  for (int it = 0; it < 9; ++it) {
    int flat = it * 256 + t;               // 0..2303
    int r = flat / 72;
    int rem = flat - r * 72;
    int n = rem >> 3, ch = rem & 7;
    int p = blk * 32 + r;
    int y = p / WW, x = p - y * WW;
    int ni = n / 3;
    int yy = y + ni - 1, xx = x + (n - ni * 3) - 1;
    v8h v = {};
    if (yy >= 0 && yy < HH && xx >= 0 && xx < WW)
      v = *(const v8h*)(feat + (yy * WW + xx) * 64 + ch * 8);
    int byte = r * 1152 + n * 128 + ch * 16;
    byte ^= (r & 7) << 4;
    *(v8h*)(lds + byte) = v;
  }
  __syncthreads();
  v4f acc[4][2] = {};
  for (int ks = 0; ks < 18; ++ks) {
    v8h bfr[2], afr[4];
    #pragma unroll
    for (int mt = 0; mt < 2; ++mt) {
      int row = mt * 16 + (lane & 15);
      int byte = row * 1152 + ks * 64 + (lane >> 4) * 16;
      byte ^= (row & 7) << 4;
      bfr[mt] = *(const v8h*)(lds + byte);
    }
    #pragma unroll
    for (int nt = 0; nt < 4; ++nt)
      afr[nt] = *(const v8h*)(w0p + (((wv * 4 + nt) * 18 + ks) * 64 + lane) * 8);
    #pragma unroll
    for (int nt = 0; nt < 4; ++nt)
      #pragma unroll
      for (int mt = 0; mt < 2; ++mt)
        acc[nt][mt] = __builtin_amdgcn_mfma_f32_16x16x32_f16(afr[nt], bfr[mt], acc[nt][mt], 0, 0, 0);
  }
  __syncthreads();
  // epilogue: D[n][m] (+b0, no relu) -> LDS [32][256] fp16
  #pragma unroll
  for (int nt = 0; nt < 4; ++nt) {
    int n0 = (wv * 4 + nt) * 16 + (lane >> 4) * 4;
    float4 bb = *(const float4*)(b0 + n0);
    #pragma unroll
    for (int mt = 0; mt < 2; ++mt) {
      int m = mt * 16 + (lane & 15);
      v4f a = acc[nt][mt];
      v4h h;
      h[0] = (_Float16)(a[0] + bb.x);
      h[1] = (_Float16)(a[1] + bb.y);
      h[2] = (_Float16)(a[2] + bb.z);
      h[3] = (_Float16)(a[3] + bb.w);
      int byte = m * 512 + n0 * 2;
      byte ^= (m & 7) << 4;
      *(v4h*)(lds + byte) = h;
    }
  }
  __syncthreads();
  // coalesced store
  #pragma unroll
  for (int i = 0; i < 4; ++i) {
    int ci = i * 256 + t;                  // 0..1023
    int m = ci >> 5, sl = ci & 31;
    int byte = m * 512 + sl * 16;
    byte ^= (m & 7) << 4;
    v8h v = *(const v8h*)(lds + byte);
    *(v8h*)(G + (size_t)(blk * 32 + m) * 256 + sl * 8) = v;
  }
}

// ---------------- one hidden layer (256->256), relu ----------------
__device__ __forceinline__ void layer256(const char* src, char* dst,
    const _Float16* __restrict__ wp, const float* __restrict__ bias,
    int lane, int wv) {
  v4f acc[4][4] = {};
  for (int ks = 0; ks < 8; ++ks) {
    v8h bfr[4], afr[4];
    #pragma unroll
    for (int mt = 0; mt < 4; ++mt) {
      int row = mt * 16 + (lane & 15);
      int byte = row * 512 + ks * 64 + (lane >> 4) * 16;
      byte ^= (row & 7) << 4;
      bfr[mt] = *(const v8h*)(src + byte);
    }
    #pragma unroll
    for (int nt = 0; nt < 4; ++nt)
      afr[nt] = *(const v8h*)(wp + (((wv * 4 + nt) * 8 + ks) * 64 + lane) * 8);
    #pragma unroll
    for (int nt = 0; nt < 4; ++nt)
      #pragma unroll
      for (int mt = 0; mt < 4; ++mt)
        acc[nt][mt] = __builtin_amdgcn_mfma_f32_16x16x32_f16(afr[nt], bfr[mt], acc[nt][mt], 0, 0, 0);
  }
  #pragma unroll
  for (int nt = 0; nt < 4; ++nt) {
    int n0 = (wv * 4 + nt) * 16 + (lane >> 4) * 4;
    float4 bb = *(const float4*)(bias + n0);
    #pragma unroll
    for (int mt = 0; mt < 4; ++mt) {
      int m = mt * 16 + (lane & 15);
      v4f a = acc[nt][mt];
      v4h h;
      h[0] = (_Float16)fmaxf(a[0] + bb.x, 0.f);
      h[1] = (_Float16)fmaxf(a[1] + bb.y, 0.f);
      h[2] = (_Float16)fmaxf(a[2] + bb.z, 0.f);
      h[3] = (_Float16)fmaxf(a[3] + bb.w, 0.f);
      int byte = m * 512 + n0 * 2;
      byte ^= (m & 7) << 4;
      *(v4h*)(dst + byte) = h;
    }
  }
}

// ---------------- fused MLP over 64 samples/block (16 queries) ----------------
__global__ __launch_bounds__(256) void k_mlp(
    const _Float16* __restrict__ G, const float4* __restrict__ qtab,
    const float* __restrict__ cell, const float* __restrict__ w0,
    const _Float16* __restrict__ w1p, const _Float16* __restrict__ w2p,
    const _Float16* __restrict__ w3p, const _Float16* __restrict__ w4p,
    const float* __restrict__ b1, const float* __restrict__ b2,
    const float* __restrict__ b3, const float* __restrict__ b4,
    float* __restrict__ out) {
  __shared__ __align__(16) char bufA[64 * 512];
  __shared__ __align__(16) char bufB[64 * 512];
  int t = threadIdx.x, blk = blockIdx.x;
  int lane = t & 63, wv = t >> 6;
  // ---- phase 0: h1 = relu(G[pix] + rel-terms) -> bufA ----
  {
    int r = t >> 2, part = t & 3;
    int s = blk * 64 + r;
    float4 qe = qtab[s];
    int lin = __float_as_int(qe.x);
    float rel0 = qe.y, rel1 = qe.z;
    int q = s >> 2;
    float rc0 = cell[q * 2 + 0] * 192.f, rc1 = cell[q * 2 + 1] * 192.f;
    const _Float16* grow = G + (size_t)lin * 256;
    const float* wr = w0 + 576 * 256;   // rows 576..579
    int c0 = part * 64;
    #pragma unroll
    for (int g8 = 0; g8 < 8; ++g8) {
      int c = c0 + g8 * 8;
      v8h gv = *(const v8h*)(grow + c);
      v8h hv;
      #pragma unroll
      for (int hf = 0; hf < 2; ++hf) {
        int cc = c + hf * 4;
        const float* w0r = wr + cc;
        #pragma unroll
        for (int j = 0; j < 4; ++j) {
          float v = (float)gv[hf * 4 + j]
                  + rel0 * w0r[j] + rel1 * w0r[256 + j]
                  + rc0 * w0r[512 + j] + rc1 * w0r[768 + j];
          hv[hf * 4 + j] = (_Float16)fmaxf(v, 0.f);
        }
      }
      int byte = r * 512 + c * 2;
      byte ^= (r & 7) << 4;
      *(v8h*)(bufA + byte) = hv;
    }
  }
  __syncthreads();
  layer256(bufA, bufB, w1p, b1, lane, wv);
  __syncthreads();
  layer256(bufB, bufA, w2p, b2, lane, wv);
  __syncthreads();
  layer256(bufA, bufB, w3p, b3, lane, wv);
  __syncthreads();
  // ---- layer 4 (256 -> 3, N padded to 16) + weighted combine ----
  v4f acc = {};
  for (int ks = 0; ks < 8; ++ks) {
    int row = wv * 16 + (lane & 15);
    int byte = row * 512 + ks * 64 + (lane >> 4) * 16;
    byte ^= (row & 7) << 4;
    v8h bfr = *(const v8h*)(bufB + byte);
    v8h afr = *(const v8h*)(w4p + (ks * 64 + lane) * 8);
    acc = __builtin_amdgcn_mfma_f32_16x16x32_f16(afr, bfr, acc, 0, 0, 0);
  }
  int mloc = lane & 15;
  int s4 = blk * 64 + wv * 16 + mloc;
  float wk = qtab[s4].w;
  float v0 = (acc[0] + b4[0]) * wk;
  float v1 = (acc[1] + b4[1]) * wk;
  float v2 = (acc[2] + b4[2]) * wk;
  v0 += __shfl_xor(v0, 1); v0 += __shfl_xor(v0, 2);
  v1 += __shfl_xor(v1, 1); v1 += __shfl_xor(v1, 2);
  v2 += __shfl_xor(v2, 1); v2 += __shfl_xor(v2, 2);
  if ((lane >> 4) == 0 && (mloc & 3) == 0) {
    int q = blk * 16 + wv * 4 + (mloc >> 2);
    out[q * 3 + 0] = v0;
    out[q * 3 + 1] = v1;
    out[q * 3 + 2] = v2;
  }
}

extern "C" void kernel_launch(void* const* d_in, const int* in_sizes, int n_in,
                              void* d_out, int out_size, void* d_ws, size_t ws_size,
                              hipStream_t stream) {
  const float* inp   = (const float*)d_in[0];
  const float* coord = (const float*)d_in[1];
  const float* cell  = (const float*)d_in[2];
  const float* enc_w = (const float*)d_in[3];
  const float* enc_b = (const float*)d_in[4];
  const float* w0 = (const float*)d_in[5];
  const float* b0 = (const float*)d_in[6];
  const float* w1 = (const float*)d_in[7];
  const float* b1 = (const float*)d_in[8];
  const float* w2 = (const float*)d_in[9];
  const float* b2 = (const float*)d_in[10];
  const float* w3 = (const float*)d_in[11];
  const float* b3 = (const float*)d_in[12];
  const float* w4 = (const float*)d_in[13];
  const float* b4 = (const float*)d_in[14];
  char* ws = (char*)d_ws;
  _Float16* feat = (_Float16*)(ws + OFF_FEAT);
  _Float16* G    = (_Float16*)(ws + OFF_G);
  float4*   qtab = (float4*)(ws + OFF_QTAB);
  _Float16* w0p  = (_Float16*)(ws + OFF_W0P);
  _Float16* w1p  = (_Float16*)(ws + OFF_W1P);
  _Float16* w2p  = (_Float16*)(ws + OFF_W2P);
  _Float16* w3p  = (_Float16*)(ws + OFF_W3P);
  _Float16* w4p  = (_Float16*)(ws + OFF_W4P);
  float*    ewt  = (float*)(ws + OFF_EWT);

  k_pack<<<(16 * 18 * 512) / 256, 256, 0, stream>>>(w0, w0p, 576, 256, 18, 16, 1);
  k_pack<<<(16 * 8 * 512) / 256, 256, 0, stream>>>(w1, w1p, 256, 256, 8, 16, 0);
  k_pack<<<(16 * 8 * 512) / 256, 256, 0, stream>>>(w2, w2p, 256, 256, 8, 16, 0);
  k_pack<<<(16 * 8 * 512) / 256, 256, 0, stream>>>(w3, w3p, 256, 256, 8, 16, 0);
  k_pack<<<(1 * 8 * 512) / 256, 256, 0, stream>>>(w4, w4p, 256, 3, 8, 1, 0);
  k_packew<<<7, 256, 0, stream>>>(enc_w, ewt);
  k_conv<<<(PIX * 64) / 256, 256, 0, stream>>>(inp, ewt, enc_b, feat);
  k_qsetup<<<65536 / 256, 256, 0, stream>>>(coord, qtab);
  k_ggemm<<<PIX / 32, 256, 0, stream>>>(feat, w0p, b0, G);
  k_mlp<<<(65536 * 4) / 64, 256, 0, stream>>>(G, qtab, cell, w0,
      w1p, w2p, w3p, w4p, b1, b2, b3, b4, (float*)d_out);
}

// Round 3
// 273.097 us; speedup vs baseline: 1.0529x; 1.0529x over previous
//
#include <hip/hip_runtime.h>

typedef _Float16 v8h __attribute__((ext_vector_type(8)));
typedef _Float16 v4h __attribute__((ext_vector_type(4)));
typedef float    v4f __attribute__((ext_vector_type(4)));

#define HH 192
#define WW 192
#define PIX (HH*WW)

// ---------------- ws layout (bytes) ----------------
static const size_t OFF_FEAT = 0;
static const size_t OFF_G    = 4718592;
static const size_t OFF_QTAB = 23592960;
static const size_t OFF_W0P  = 27787264;
static const size_t OFF_W1P  = 28082176;
static const size_t OFF_W2P  = 28213248;
static const size_t OFF_W3P  = 28344320;
static const size_t OFF_W4P  = 28475392;
static const size_t OFF_EWT  = 28483584;
static const size_t OFF_WTP  = 28490496;  // 32ch*4row*8col fp16 = 1024 elem = 2048 B

// ---------------- weight prepack ----------------
__global__ __launch_bounds__(256) void k_pack(const float* __restrict__ src,
    _Float16* __restrict__ dst, int K, int N, int KS, int NT, int mode) {
  int gid = blockIdx.x * 256 + threadIdx.x;
  int total = NT * KS * 512;
  if (gid >= total) return;
  int j  = gid & 7;
  int l  = (gid >> 3) & 63;
  int ks = (gid >> 9) % KS;
  int nt = gid / (512 * KS);
  int k   = ks * 32 + ((l >> 4) << 3) + j;
  int col = nt * 16 + (l & 15);
  float v = 0.f;
  if (col < N && k < K) {
    int row = (mode == 1) ? ((k & 63) * 9 + (k >> 6)) : k;
    v = src[row * N + col];
  }
  dst[gid] = (_Float16)v;
}

// ewt[tap*64 + c] = ew[c*27 + tap]
__global__ __launch_bounds__(256) void k_packew(const float* __restrict__ ew,
                                                float* __restrict__ ewt) {
  int i = blockIdx.x * 256 + threadIdx.x;
  if (i >= 27 * 64) return;
  int tap = i >> 6, c = i & 63;
  ewt[i] = ew[c * 27 + tap];
}

// wtp[(ch*4 + j)*8 + col] = w0[(576+j)*256 + ch*8 + col]  (fp16 tail rows)
// 32 chunks x 4 rows x 8 cols = 1024 elements total.
__global__ __launch_bounds__(256) void k_packwt(const float* __restrict__ w0,
                                                _Float16* __restrict__ wtp) {
  int i = blockIdx.x * 256 + threadIdx.x;
  if (i >= 1024) return;
  int col = i & 7, j = (i >> 3) & 3, ch = i >> 5;
  wtp[i] = (_Float16)w0[(576 + j) * 256 + ch * 8 + col];
}

// ---------------- conv encoder: feat[p][c] fp16 ----------------
__global__ __launch_bounds__(256) void k_conv(const float* __restrict__ inp,
    const float* __restrict__ ewt, const float* __restrict__ eb,
    _Float16* __restrict__ feat) {
  int gid = blockIdx.x * 256 + threadIdx.x;
  int p = gid >> 6, c = gid & 63;
  int y = p / WW, x = p - y * WW;
  float acc = eb[c];
  #pragma unroll
  for (int ci = 0; ci < 3; ++ci) {
    #pragma unroll
    for (int dy = 0; dy < 3; ++dy) {
      #pragma unroll
      for (int dx = 0; dx < 3; ++dx) {
        int yy = y + dy - 1, xx = x + dx - 1;
        float v = (yy >= 0 && yy < HH && xx >= 0 && xx < WW)
                      ? inp[ci * PIX + yy * WW + xx] : 0.f;
        acc += v * ewt[(ci * 9 + dy * 3 + dx) * 64 + c];
      }
    }
  }
  feat[p * 64 + c] = (_Float16)acc;
}

// ---------------- query setup ----------------
__global__ __launch_bounds__(256) void k_qsetup(const float* __restrict__ coord,
                                                float4* __restrict__ qtab) {
  int q = blockIdx.x * 256 + threadIdx.x;
  float cy = coord[q * 2 + 0], cx = coord[q * 2 + 1];
  const float eps = 1e-6f;
  const float rad = (float)(1.0 / 192.0);
  const float CLO = (float)(-1.0 + 1e-6);
  const float CHI = (float)(1.0 - 1e-6);
  const float S2  = (float)(2.0 / 192.0);
  float ry[4], rx[4], ar[4];
  int   li[4];
  #pragma unroll
  for (int k = 0; k < 4; ++k) {
    float oy = (k < 2) ? -rad : rad;
    float ox = (k & 1) ? rad : -rad;
    float cey = __fadd_rn(__fadd_rn(cy, oy), eps);
    float cex = __fadd_rn(__fadd_rn(cx, ox), eps);
    cey = fminf(fmaxf(cey, CLO), CHI);
    cex = fminf(fmaxf(cex, CLO), CHI);
    float ty = __fmul_rn(__fsub_rn(__fmul_rn(__fadd_rn(cey, 1.0f), 192.0f), 1.0f), 0.5f);
    float tx = __fmul_rn(__fsub_rn(__fmul_rn(__fadd_rn(cex, 1.0f), 192.0f), 1.0f), 0.5f);
    float fy = fminf(fmaxf(rintf(ty), 0.f), 191.f);
    float fx = fminf(fmaxf(rintf(tx), 0.f), 191.f);
    float qy = __fsub_rn(__fmul_rn(__fadd_rn(fy, 0.5f), S2), 1.0f);
    float qx = __fsub_rn(__fmul_rn(__fadd_rn(fx, 0.5f), S2), 1.0f);
    ry[k] = __fmul_rn(__fsub_rn(cy, qy), 192.0f);
    rx[k] = __fmul_rn(__fsub_rn(cx, qx), 192.0f);
    ar[k] = fabsf(ry[k] * rx[k]) + 1e-9f;
    li[k] = (int)fy * WW + (int)fx;
  }
  float tot = ar[0] + ar[1] + ar[2] + ar[3];
  #pragma unroll
  for (int k = 0; k < 4; ++k) {
    float wk = ar[3 - k] / tot;
    qtab[q * 4 + k] = make_float4(__int_as_float(li[k]), ry[k], rx[k], wk);
  }
}

// ---------------- G-GEMM ----------------
__global__ __launch_bounds__(256) void k_ggemm(const _Float16* __restrict__ feat,
    const _Float16* __restrict__ w0p, const float* __restrict__ b0,
    _Float16* __restrict__ G) {
  __shared__ __align__(16) char lds[32 * 1152];
  int t = threadIdx.x, blk = blockIdx.x;
  int lane = t & 63, wv = t >> 6;
  #pragma unroll
  for (int it = 0; it < 9; ++it) {
    int flat = it * 256 + t;
    int r = flat / 72;
    int rem = flat - r * 72;
    int n = rem >> 3, ch = rem & 7;
    int p = blk * 32 + r;
    int y = p / WW, x = p - y * WW;
    int ni = n / 3;
    int yy = y + ni - 1, xx = x + (n - ni * 3) - 1;
    v8h v = {};
    if (yy >= 0 && yy < HH && xx >= 0 && xx < WW)
      v = *(const v8h*)(feat + (yy * WW + xx) * 64 + ch * 8);
    int byte = r * 1152 + n * 128 + ch * 16;
    byte ^= (r & 7) << 4;
    *(v8h*)(lds + byte) = v;
  }
  __syncthreads();
  v4f acc[4][2] = {};
  for (int ks = 0; ks < 18; ++ks) {
    v8h bfr[2], afr[4];
    #pragma unroll
    for (int mt = 0; mt < 2; ++mt) {
      int row = mt * 16 + (lane & 15);
      int byte = row * 1152 + ks * 64 + (lane >> 4) * 16;
      byte ^= (row & 7) << 4;
      bfr[mt] = *(const v8h*)(lds + byte);
    }
    #pragma unroll
    for (int nt = 0; nt < 4; ++nt)
      afr[nt] = *(const v8h*)(w0p + (((wv * 4 + nt) * 18 + ks) * 64 + lane) * 8);
    #pragma unroll
    for (int nt = 0; nt < 4; ++nt)
      #pragma unroll
      for (int mt = 0; mt < 2; ++mt)
        acc[nt][mt] = __builtin_amdgcn_mfma_f32_16x16x32_f16(afr[nt], bfr[mt], acc[nt][mt], 0, 0, 0);
  }
  __syncthreads();
  #pragma unroll
  for (int nt = 0; nt < 4; ++nt) {
    int n0 = (wv * 4 + nt) * 16 + (lane >> 4) * 4;
    float4 bb = *(const float4*)(b0 + n0);
    #pragma unroll
    for (int mt = 0; mt < 2; ++mt) {
      int m = mt * 16 + (lane & 15);
      v4f a = acc[nt][mt];
      v4h h;
      h[0] = (_Float16)(a[0] + bb.x);
      h[1] = (_Float16)(a[1] + bb.y);
      h[2] = (_Float16)(a[2] + bb.z);
      h[3] = (_Float16)(a[3] + bb.w);
      int byte = m * 512 + n0 * 2;
      byte ^= (m & 7) << 4;
      *(v4h*)(lds + byte) = h;
    }
  }
  __syncthreads();
  #pragma unroll
  for (int i = 0; i < 4; ++i) {
    int ci = i * 256 + t;
    int m = ci >> 5, sl = ci & 31;
    int byte = m * 512 + sl * 16;
    byte ^= (m & 7) << 4;
    v8h v = *(const v8h*)(lds + byte);
    *(v8h*)(G + (size_t)(blk * 32 + m) * 256 + sl * 8) = v;
  }
}

// ---------------- one hidden layer (256->256), relu, single buffer ----------------
// Every wave reads the ENTIRE buf during the ks loop, then (after a barrier)
// overwrites it with the next activations -> one 32KB buffer suffices.
__device__ __forceinline__ void layer256(char* buf,
    const _Float16* __restrict__ wp, const float* __restrict__ bias,
    int lane, int wv) {
  v4f acc[4][4] = {};
  for (int ks = 0; ks < 8; ++ks) {
    v8h bfr[4], afr[4];
    #pragma unroll
    for (int mt = 0; mt < 4; ++mt) {
      int row = mt * 16 + (lane & 15);
      int byte = row * 512 + ks * 64 + (lane >> 4) * 16;
      byte ^= (row & 7) << 4;
      bfr[mt] = *(const v8h*)(buf + byte);
    }
    #pragma unroll
    for (int nt = 0; nt < 4; ++nt)
      afr[nt] = *(const v8h*)(wp + (((wv * 4 + nt) * 8 + ks) * 64 + lane) * 8);
    #pragma unroll
    for (int nt = 0; nt < 4; ++nt)
      #pragma unroll
      for (int mt = 0; mt < 4; ++mt)
        acc[nt][mt] = __builtin_amdgcn_mfma_f32_16x16x32_f16(afr[nt], bfr[mt], acc[nt][mt], 0, 0, 0);
  }
  __syncthreads();   // all reads of buf complete
  #pragma unroll
  for (int nt = 0; nt < 4; ++nt) {
    int n0 = (wv * 4 + nt) * 16 + (lane >> 4) * 4;
    float4 bb = *(const float4*)(bias + n0);
    #pragma unroll
    for (int mt = 0; mt < 4; ++mt) {
      int m = mt * 16 + (lane & 15);
      v4f a = acc[nt][mt];
      v4h h;
      h[0] = (_Float16)fmaxf(a[0] + bb.x, 0.f);
      h[1] = (_Float16)fmaxf(a[1] + bb.y, 0.f);
      h[2] = (_Float16)fmaxf(a[2] + bb.z, 0.f);
      h[3] = (_Float16)fmaxf(a[3] + bb.w, 0.f);
      int byte = m * 512 + n0 * 2;
      byte ^= (m & 7) << 4;
      *(v4h*)(buf + byte) = h;
    }
  }
  __syncthreads();   // writes visible before next layer reads
}

// ---------------- fused MLP over 64 samples/block ----------------
__global__ __launch_bounds__(256, 4) void k_mlp(
    const _Float16* __restrict__ G, const float4* __restrict__ qtab,
    const float* __restrict__ cell, const _Float16* __restrict__ wtp,
    const _Float16* __restrict__ w1p, const _Float16* __restrict__ w2p,
    const _Float16* __restrict__ w3p, const _Float16* __restrict__ w4p,
    const float* __restrict__ b1, const float* __restrict__ b2,
    const float* __restrict__ b3, const float* __restrict__ b4,
    float* __restrict__ out) {
  __shared__ __align__(16) char buf[64 * 512];
  int t = threadIdx.x, blk = blockIdx.x;
  int lane = t & 63, wv = t >> 6;
  // ---- phase 0: h1 = relu(G[pix] + tail-terms) -> buf ----
  // thread = (row-group, 16B col chunk): each wave's write covers two full
  // contiguous 512B rows -> conflict-free ds_write_b128.
  {
    int ch = t & 31;           // col chunk: features ch*8 .. ch*8+7
    int r8 = t >> 5;           // row group 0..7
    const _Float16* wtb = wtp + ch * 32;
    v8h wt0 = *(const v8h*)(wtb);
    v8h wt1 = *(const v8h*)(wtb + 8);
    v8h wt2 = *(const v8h*)(wtb + 16);
    v8h wt3 = *(const v8h*)(wtb + 24);
    #pragma unroll
    for (int g = 0; g < 8; ++g) {
      int r = g * 8 + r8;
      int s = blk * 64 + r;
      float4 qe = qtab[s];
      int lin = __float_as_int(qe.x);
      float rel0 = qe.y, rel1 = qe.z;
      int q = s >> 2;
      float rc0 = cell[q * 2 + 0] * 192.f, rc1 = cell[q * 2 + 1] * 192.f;
      v8h gv = *(const v8h*)(G + (size_t)lin * 256 + ch * 8);
      v8h hv;
      #pragma unroll
      for (int i = 0; i < 8; ++i) {
        float v = (float)gv[i] + rel0 * (float)wt0[i] + rel1 * (float)wt1[i]
                + rc0 * (float)wt2[i] + rc1 * (float)wt3[i];
        hv[i] = (_Float16)fmaxf(v, 0.f);
      }
      int byte = r * 512 + ch * 16;
      byte ^= (r & 7) << 4;
      *(v8h*)(buf + byte) = hv;
    }
  }
  __syncthreads();
  layer256(buf, w1p, b1, lane, wv);
  layer256(buf, w2p, b2, lane, wv);
  layer256(buf, w3p, b3, lane, wv);
  // ---- layer 4 (256 -> 3, N padded to 16) + weighted combine ----
  v4f acc = {};
  for (int ks = 0; ks < 8; ++ks) {
    int row = wv * 16 + (lane & 15);
    int byte = row * 512 + ks * 64 + (lane >> 4) * 16;
    byte ^= (row & 7) << 4;
    v8h bfr = *(const v8h*)(buf + byte);
    v8h afr = *(const v8h*)(w4p + (ks * 64 + lane) * 8);
    acc = __builtin_amdgcn_mfma_f32_16x16x32_f16(afr, bfr, acc, 0, 0, 0);
  }
  int mloc = lane & 15;
  int s4 = blk * 64 + wv * 16 + mloc;
  float wk = qtab[s4].w;
  float v0 = (acc[0] + b4[0]) * wk;
  float v1 = (acc[1] + b4[1]) * wk;
  float v2 = (acc[2] + b4[2]) * wk;
  v0 += __shfl_xor(v0, 1); v0 += __shfl_xor(v0, 2);
  v1 += __shfl_xor(v1, 1); v1 += __shfl_xor(v1, 2);
  v2 += __shfl_xor(v2, 1); v2 += __shfl_xor(v2, 2);
  if ((lane >> 4) == 0 && (mloc & 3) == 0) {
    int q = blk * 16 + wv * 4 + (mloc >> 2);
    out[q * 3 + 0] = v0;
    out[q * 3 + 1] = v1;
    out[q * 3 + 2] = v2;
  }
}

extern "C" void kernel_launch(void* const* d_in, const int* in_sizes, int n_in,
                              void* d_out, int out_size, void* d_ws, size_t ws_size,
                              hipStream_t stream) {
  const float* inp   = (const float*)d_in[0];
  const float* coord = (const float*)d_in[1];
  const float* cell  = (const float*)d_in[2];
  const float* enc_w = (const float*)d_in[3];
  const float* enc_b = (const float*)d_in[4];
  const float* w0 = (const float*)d_in[5];
  const float* b0 = (const float*)d_in[6];
  const float* w1 = (const float*)d_in[7];
  const float* b1 = (const float*)d_in[8];
  const float* w2 = (const float*)d_in[9];
  const float* b2 = (const float*)d_in[10];
  const float* w3 = (const float*)d_in[11];
  const float* b3 = (const float*)d_in[12];
  const float* w4 = (const float*)d_in[13];
  const float* b4 = (const float*)d_in[14];
  char* ws = (char*)d_ws;
  _Float16* feat = (_Float16*)(ws + OFF_FEAT);
  _Float16* G    = (_Float16*)(ws + OFF_G);
  float4*   qtab = (float4*)(ws + OFF_QTAB);
  _Float16* w0p  = (_Float16*)(ws + OFF_W0P);
  _Float16* w1p  = (_Float16*)(ws + OFF_W1P);
  _Float16* w2p  = (_Float16*)(ws + OFF_W2P);
  _Float16* w3p  = (_Float16*)(ws + OFF_W3P);
  _Float16* w4p  = (_Float16*)(ws + OFF_W4P);
  float*    ewt  = (float*)(ws + OFF_EWT);
  _Float16* wtp  = (_Float16*)(ws + OFF_WTP);

  k_pack<<<(16 * 18 * 512) / 256, 256, 0, stream>>>(w0, w0p, 576, 256, 18, 16, 1);
  k_pack<<<(16 * 8 * 512) / 256, 256, 0, stream>>>(w1, w1p, 256, 256, 8, 16, 0);
  k_pack<<<(16 * 8 * 512) / 256, 256, 0, stream>>>(w2, w2p, 256, 256, 8, 16, 0);
  k_pack<<<(16 * 8 * 512) / 256, 256, 0, stream>>>(w3, w3p, 256, 256, 8, 16, 0);
  k_pack<<<(1 * 8 * 512) / 256, 256, 0, stream>>>(w4, w4p, 256, 3, 8, 1, 0);
  k_packew<<<7, 256, 0, stream>>>(enc_w, ewt);
  k_packwt<<<4, 256, 0, stream>>>(w0, wtp);
  k_conv<<<(PIX * 64) / 256, 256, 0, stream>>>(inp, ewt, enc_b, feat);
  k_qsetup<<<65536 / 256, 256, 0, stream>>>(coord, qtab);
  k_ggemm<<<PIX / 32, 256, 0, stream>>>(feat, w0p, b0, G);
  k_mlp<<<(65536 * 4) / 64, 256, 0, stream>>>(G, qtab, cell, wtp,
      w1p, w2p, w3p, w4p, b1, b2, b3, b4, (float*)d_out);
}

// Round 4
// 193.260 us; speedup vs baseline: 1.4879x; 1.4131x over previous
//
#include <hip/hip_runtime.h>

typedef _Float16 v8h __attribute__((ext_vector_type(8)));
typedef _Float16 v4h __attribute__((ext_vector_type(4)));
typedef float    v4f __attribute__((ext_vector_type(4)));

#define HH 192
#define WW 192
#define PIX (HH*WW)

// ---------------- ws layout (bytes) ----------------
static const size_t OFF_FEAT = 0;
static const size_t OFF_G    = 4718592;
static const size_t OFF_QTAB = 23592960;
static const size_t OFF_W0P  = 27787264;
static const size_t OFF_W1P  = 28082176;
static const size_t OFF_W2P  = 28213248;
static const size_t OFF_W3P  = 28344320;
static const size_t OFF_W4P  = 28475392;
static const size_t OFF_EWT  = 28483584;
static const size_t OFF_WTP  = 28490496;  // 32ch*4row*8col fp16 = 1024 elem = 2048 B

// ---------------- weight prepack ----------------
__global__ __launch_bounds__(256) void k_pack(const float* __restrict__ src,
    _Float16* __restrict__ dst, int K, int N, int KS, int NT, int mode) {
  int gid = blockIdx.x * 256 + threadIdx.x;
  int total = NT * KS * 512;
  if (gid >= total) return;
  int j  = gid & 7;
  int l  = (gid >> 3) & 63;
  int ks = (gid >> 9) % KS;
  int nt = gid / (512 * KS);
  int k   = ks * 32 + ((l >> 4) << 3) + j;
  int col = nt * 16 + (l & 15);
  float v = 0.f;
  if (col < N && k < K) {
    int row = (mode == 1) ? ((k & 63) * 9 + (k >> 6)) : k;
    v = src[row * N + col];
  }
  dst[gid] = (_Float16)v;
}

// ewt[tap*64 + c] = ew[c*27 + tap]
__global__ __launch_bounds__(256) void k_packew(const float* __restrict__ ew,
                                                float* __restrict__ ewt) {
  int i = blockIdx.x * 256 + threadIdx.x;
  if (i >= 27 * 64) return;
  int tap = i >> 6, c = i & 63;
  ewt[i] = ew[c * 27 + tap];
}

// wtp[(ch*4 + j)*8 + col] = w0[(576+j)*256 + ch*8 + col]  (fp16 tail rows)
// 32 chunks x 4 rows x 8 cols = 1024 elements total.
__global__ __launch_bounds__(256) void k_packwt(const float* __restrict__ w0,
                                                _Float16* __restrict__ wtp) {
  int i = blockIdx.x * 256 + threadIdx.x;
  if (i >= 1024) return;
  int col = i & 7, j = (i >> 3) & 3, ch = i >> 5;
  wtp[i] = (_Float16)w0[(576 + j) * 256 + ch * 8 + col];
}

// ---------------- conv encoder: feat[p][c] fp16 ----------------
__global__ __launch_bounds__(256) void k_conv(const float* __restrict__ inp,
    const float* __restrict__ ewt, const float* __restrict__ eb,
    _Float16* __restrict__ feat) {
  int gid = blockIdx.x * 256 + threadIdx.x;
  int p = gid >> 6, c = gid & 63;
  int y = p / WW, x = p - y * WW;
  float acc = eb[c];
  #pragma unroll
  for (int ci = 0; ci < 3; ++ci) {
    #pragma unroll
    for (int dy = 0; dy < 3; ++dy) {
      #pragma unroll
      for (int dx = 0; dx < 3; ++dx) {
        int yy = y + dy - 1, xx = x + dx - 1;
        float v = (yy >= 0 && yy < HH && xx >= 0 && xx < WW)
                      ? inp[ci * PIX + yy * WW + xx] : 0.f;
        acc += v * ewt[(ci * 9 + dy * 3 + dx) * 64 + c];
      }
    }
  }
  feat[p * 64 + c] = (_Float16)acc;
}

// ---------------- query setup ----------------
__global__ __launch_bounds__(256) void k_qsetup(const float* __restrict__ coord,
                                                float4* __restrict__ qtab) {
  int q = blockIdx.x * 256 + threadIdx.x;
  float cy = coord[q * 2 + 0], cx = coord[q * 2 + 1];
  const float eps = 1e-6f;
  const float rad = (float)(1.0 / 192.0);
  const float CLO = (float)(-1.0 + 1e-6);
  const float CHI = (float)(1.0 - 1e-6);
  const float S2  = (float)(2.0 / 192.0);
  float ry[4], rx[4], ar[4];
  int   li[4];
  #pragma unroll
  for (int k = 0; k < 4; ++k) {
    float oy = (k < 2) ? -rad : rad;
    float ox = (k & 1) ? rad : -rad;
    float cey = __fadd_rn(__fadd_rn(cy, oy), eps);
    float cex = __fadd_rn(__fadd_rn(cx, ox), eps);
    cey = fminf(fmaxf(cey, CLO), CHI);
    cex = fminf(fmaxf(cex, CLO), CHI);
    float ty = __fmul_rn(__fsub_rn(__fmul_rn(__fadd_rn(cey, 1.0f), 192.0f), 1.0f), 0.5f);
    float tx = __fmul_rn(__fsub_rn(__fmul_rn(__fadd_rn(cex, 1.0f), 192.0f), 1.0f), 0.5f);
    float fy = fminf(fmaxf(rintf(ty), 0.f), 191.f);
    float fx = fminf(fmaxf(rintf(tx), 0.f), 191.f);
    float qy = __fsub_rn(__fmul_rn(__fadd_rn(fy, 0.5f), S2), 1.0f);
    float qx = __fsub_rn(__fmul_rn(__fadd_rn(fx, 0.5f), S2), 1.0f);
    ry[k] = __fmul_rn(__fsub_rn(cy, qy), 192.0f);
    rx[k] = __fmul_rn(__fsub_rn(cx, qx), 192.0f);
    ar[k] = fabsf(ry[k] * rx[k]) + 1e-9f;
    li[k] = (int)fy * WW + (int)fx;
  }
  float tot = ar[0] + ar[1] + ar[2] + ar[3];
  #pragma unroll
  for (int k = 0; k < 4; ++k) {
    float wk = ar[3 - k] / tot;
    qtab[q * 4 + k] = make_float4(__int_as_float(li[k]), ry[k], rx[k], wk);
  }
}

// ---------------- G-GEMM ----------------
__global__ __launch_bounds__(256) void k_ggemm(const _Float16* __restrict__ feat,
    const _Float16* __restrict__ w0p, const float* __restrict__ b0,
    _Float16* __restrict__ G) {
  __shared__ __align__(16) char lds[32 * 1152];
  int t = threadIdx.x, blk = blockIdx.x;
  int lane = t & 63, wv = t >> 6;
  #pragma unroll
  for (int it = 0; it < 9; ++it) {
    int flat = it * 256 + t;
    int r = flat / 72;
    int rem = flat - r * 72;
    int n = rem >> 3, ch = rem & 7;
    int p = blk * 32 + r;
    int y = p / WW, x = p - y * WW;
    int ni = n / 3;
    int yy = y + ni - 1, xx = x + (n - ni * 3) - 1;
    v8h v = {};
    if (yy >= 0 && yy < HH && xx >= 0 && xx < WW)
      v = *(const v8h*)(feat + (yy * WW + xx) * 64 + ch * 8);
    int byte = r * 1152 + n * 128 + ch * 16;
    byte ^= (r & 7) << 4;
    *(v8h*)(lds + byte) = v;
  }
  __syncthreads();
  v4f acc[4][2] = {};
  for (int ks = 0; ks < 18; ++ks) {
    v8h bfr[2], afr[4];
    #pragma unroll
    for (int mt = 0; mt < 2; ++mt) {
      int row = mt * 16 + (lane & 15);
      int byte = row * 1152 + ks * 64 + (lane >> 4) * 16;
      byte ^= (row & 7) << 4;
      bfr[mt] = *(const v8h*)(lds + byte);
    }
    #pragma unroll
    for (int nt = 0; nt < 4; ++nt)
      afr[nt] = *(const v8h*)(w0p + (((wv * 4 + nt) * 18 + ks) * 64 + lane) * 8);
    #pragma unroll
    for (int nt = 0; nt < 4; ++nt)
      #pragma unroll
      for (int mt = 0; mt < 2; ++mt)
        acc[nt][mt] = __builtin_amdgcn_mfma_f32_16x16x32_f16(afr[nt], bfr[mt], acc[nt][mt], 0, 0, 0);
  }
  __syncthreads();
  #pragma unroll
  for (int nt = 0; nt < 4; ++nt) {
    int n0 = (wv * 4 + nt) * 16 + (lane >> 4) * 4;
    float4 bb = *(const float4*)(b0 + n0);
    #pragma unroll
    for (int mt = 0; mt < 2; ++mt) {
      int m = mt * 16 + (lane & 15);
      v4f a = acc[nt][mt];
      v4h h;
      h[0] = (_Float16)(a[0] + bb.x);
      h[1] = (_Float16)(a[1] + bb.y);
      h[2] = (_Float16)(a[2] + bb.z);
      h[3] = (_Float16)(a[3] + bb.w);
      int byte = m * 512 + n0 * 2;
      byte ^= (m & 7) << 4;
      *(v4h*)(lds + byte) = h;
    }
  }
  __syncthreads();
  #pragma unroll
  for (int i = 0; i < 4; ++i) {
    int ci = i * 256 + t;
    int m = ci >> 5, sl = ci & 31;
    int byte = m * 512 + sl * 16;
    byte ^= (m & 7) << 4;
    v8h v = *(const v8h*)(lds + byte);
    *(v8h*)(G + (size_t)(blk * 32 + m) * 256 + sl * 8) = v;
  }
}

// ---------------- one hidden layer (256->256), relu, single buffer ----------------
// Every wave reads the ENTIRE buf during the ks loop, then (after a barrier)
// overwrites it with the next activations -> one 32KB buffer suffices.
__device__ __forceinline__ void layer256(char* buf,
    const _Float16* __restrict__ wp, const float* __restrict__ bias,
    int lane, int wv) {
  v4f acc[4][4] = {};
  for (int ks = 0; ks < 8; ++ks) {
    v8h bfr[4], afr[4];
    #pragma unroll
    for (int mt = 0; mt < 4; ++mt) {
      int row = mt * 16 + (lane & 15);
      int byte = row * 512 + ks * 64 + (lane >> 4) * 16;
      byte ^= (row & 7) << 4;
      bfr[mt] = *(const v8h*)(buf + byte);
    }
    #pragma unroll
    for (int nt = 0; nt < 4; ++nt)
      afr[nt] = *(const v8h*)(wp + (((wv * 4 + nt) * 8 + ks) * 64 + lane) * 8);
    #pragma unroll
    for (int nt = 0; nt < 4; ++nt)
      #pragma unroll
      for (int mt = 0; mt < 4; ++mt)
        acc[nt][mt] = __builtin_amdgcn_mfma_f32_16x16x32_f16(afr[nt], bfr[mt], acc[nt][mt], 0, 0, 0);
  }
  __syncthreads();   // all reads of buf complete
  #pragma unroll
  for (int nt = 0; nt < 4; ++nt) {
    int n0 = (wv * 4 + nt) * 16 + (lane >> 4) * 4;
    float4 bb = *(const float4*)(bias + n0);
    #pragma unroll
    for (int mt = 0; mt < 4; ++mt) {
      int m = mt * 16 + (lane & 15);
      v4f a = acc[nt][mt];
      v4h h;
      h[0] = (_Float16)fmaxf(a[0] + bb.x, 0.f);
      h[1] = (_Float16)fmaxf(a[1] + bb.y, 0.f);
      h[2] = (_Float16)fmaxf(a[2] + bb.z, 0.f);
      h[3] = (_Float16)fmaxf(a[3] + bb.w, 0.f);
      int byte = m * 512 + n0 * 2;
      byte ^= (m & 7) << 4;
      *(v4h*)(buf + byte) = h;
    }
  }
  __syncthreads();   // writes visible before next layer reads
}

// ---------------- fused MLP over 64 samples/block ----------------
// NOTE: no min-waves hint — __launch_bounds__(256,4) capped VGPRs at 64 and
// spilled acc to scratch (222MB WRITE_SIZE, +190MB FETCH). Natural ~112 VGPR
// gives 4 waves/EU anyway; LDS 32KB allows 5 blocks/CU.
__global__ __launch_bounds__(256) void k_mlp(
    const _Float16* __restrict__ G, const float4* __restrict__ qtab,
    const float* __restrict__ cell, const _Float16* __restrict__ wtp,
    const _Float16* __restrict__ w1p, const _Float16* __restrict__ w2p,
    const _Float16* __restrict__ w3p, const _Float16* __restrict__ w4p,
    const float* __restrict__ b1, const float* __restrict__ b2,
    const float* __restrict__ b3, const float* __restrict__ b4,
    float* __restrict__ out) {
  __shared__ __align__(16) char buf[64 * 512];
  int t = threadIdx.x, blk = blockIdx.x;
  int lane = t & 63, wv = t >> 6;
  // ---- phase 0: h1 = relu(G[pix] + tail-terms) -> buf ----
  {
    int ch = t & 31;           // col chunk: features ch*8 .. ch*8+7
    int r8 = t >> 5;           // row group 0..7
    const _Float16* wtb = wtp + ch * 32;
    v8h wt0 = *(const v8h*)(wtb);
    v8h wt1 = *(const v8h*)(wtb + 8);
    v8h wt2 = *(const v8h*)(wtb + 16);
    v8h wt3 = *(const v8h*)(wtb + 24);
    #pragma unroll
    for (int g = 0; g < 8; ++g) {
      int r = g * 8 + r8;
      int s = blk * 64 + r;
      float4 qe = qtab[s];
      int lin = __float_as_int(qe.x);
      float rel0 = qe.y, rel1 = qe.z;
      int q = s >> 2;
      float rc0 = cell[q * 2 + 0] * 192.f, rc1 = cell[q * 2 + 1] * 192.f;
      v8h gv = *(const v8h*)(G + (size_t)lin * 256 + ch * 8);
      v8h hv;
      #pragma unroll
      for (int i = 0; i < 8; ++i) {
        float v = (float)gv[i] + rel0 * (float)wt0[i] + rel1 * (float)wt1[i]
                + rc0 * (float)wt2[i] + rc1 * (float)wt3[i];
        hv[i] = (_Float16)fmaxf(v, 0.f);
      }
      int byte = r * 512 + ch * 16;
      byte ^= (r & 7) << 4;
      *(v8h*)(buf + byte) = hv;
    }
  }
  __syncthreads();
  layer256(buf, w1p, b1, lane, wv);
  layer256(buf, w2p, b2, lane, wv);
  layer256(buf, w3p, b3, lane, wv);
  // ---- layer 4 (256 -> 3, N padded to 16) + weighted combine ----
  v4f acc = {};
  for (int ks = 0; ks < 8; ++ks) {
    int row = wv * 16 + (lane & 15);
    int byte = row * 512 + ks * 64 + (lane >> 4) * 16;
    byte ^= (row & 7) << 4;
    v8h bfr = *(const v8h*)(buf + byte);
    v8h afr = *(const v8h*)(w4p + (ks * 64 + lane) * 8);
    acc = __builtin_amdgcn_mfma_f32_16x16x32_f16(afr, bfr, acc, 0, 0, 0);
  }
  int mloc = lane & 15;
  int s4 = blk * 64 + wv * 16 + mloc;
  float wk = qtab[s4].w;
  float v0 = (acc[0] + b4[0]) * wk;
  float v1 = (acc[1] + b4[1]) * wk;
  float v2 = (acc[2] + b4[2]) * wk;
  v0 += __shfl_xor(v0, 1); v0 += __shfl_xor(v0, 2);
  v1 += __shfl_xor(v1, 1); v1 += __shfl_xor(v1, 2);
  v2 += __shfl_xor(v2, 1); v2 += __shfl_xor(v2, 2);
  if ((lane >> 4) == 0 && (mloc & 3) == 0) {
    int q = blk * 16 + wv * 4 + (mloc >> 2);
    out[q * 3 + 0] = v0;
    out[q * 3 + 1] = v1;
    out[q * 3 + 2] = v2;
  }
}

extern "C" void kernel_launch(void* const* d_in, const int* in_sizes, int n_in,
                              void* d_out, int out_size, void* d_ws, size_t ws_size,
                              hipStream_t stream) {
  const float* inp   = (const float*)d_in[0];
  const float* coord = (const float*)d_in[1];
  const float* cell  = (const float*)d_in[2];
  const float* enc_w = (const float*)d_in[3];
  const float* enc_b = (const float*)d_in[4];
  const float* w0 = (const float*)d_in[5];
  const float* b0 = (const float*)d_in[6];
  const float* w1 = (const float*)d_in[7];
  const float* b1 = (const float*)d_in[8];
  const float* w2 = (const float*)d_in[9];
  const float* b2 = (const float*)d_in[10];
  const float* w3 = (const float*)d_in[11];
  const float* b3 = (const float*)d_in[12];
  const float* w4 = (const float*)d_in[13];
  const float* b4 = (const float*)d_in[14];
  char* ws = (char*)d_ws;
  _Float16* feat = (_Float16*)(ws + OFF_FEAT);
  _Float16* G    = (_Float16*)(ws + OFF_G);
  float4*   qtab = (float4*)(ws + OFF_QTAB);
  _Float16* w0p  = (_Float16*)(ws + OFF_W0P);
  _Float16* w1p  = (_Float16*)(ws + OFF_W1P);
  _Float16* w2p  = (_Float16*)(ws + OFF_W2P);
  _Float16* w3p  = (_Float16*)(ws + OFF_W3P);
  _Float16* w4p  = (_Float16*)(ws + OFF_W4P);
  float*    ewt  = (float*)(ws + OFF_EWT);
  _Float16* wtp  = (_Float16*)(ws + OFF_WTP);

  k_pack<<<(16 * 18 * 512) / 256, 256, 0, stream>>>(w0, w0p, 576, 256, 18, 16, 1);
  k_pack<<<(16 * 8 * 512) / 256, 256, 0, stream>>>(w1, w1p, 256, 256, 8, 16, 0);
  k_pack<<<(16 * 8 * 512) / 256, 256, 0, stream>>>(w2, w2p, 256, 256, 8, 16, 0);
  k_pack<<<(16 * 8 * 512) / 256, 256, 0, stream>>>(w3, w3p, 256, 256, 8, 16, 0);
  k_pack<<<(1 * 8 * 512) / 256, 256, 0, stream>>>(w4, w4p, 256, 3, 8, 1, 0);
  k_packew<<<7, 256, 0, stream>>>(enc_w, ewt);
  k_packwt<<<4, 256, 0, stream>>>(w0, wtp);
  k_conv<<<(PIX * 64) / 256, 256, 0, stream>>>(inp, ewt, enc_b, feat);
  k_qsetup<<<65536 / 256, 256, 0, stream>>>(coord, qtab);
  k_ggemm<<<PIX / 32, 256, 0, stream>>>(feat, w0p, b0, G);
  k_mlp<<<(65536 * 4) / 64, 256, 0, stream>>>(G, qtab, cell, wtp,
      w1p, w2p, w3p, w4p, b1, b2, b3, b4, (float*)d_out);
}